// Round 10
// baseline (257.705 us; speedup 1.0000x reference)
//
#include <hip/hip_runtime.h>

// out[b, w, j] = sum_p x[b,j,p] * weight[j,p,w] + bias[j,w]
// x: [B,M,P] f32, weight: [M,P,W] f32, bias: [M,W] f32, out: [B,W,M] f32
// B=128, M=10000, P=64, W=24. HBM floor ~510 MB -> ~82 us.
//
// Round-10 = round-8 structure, staging fully fixed. Round-8 staged 768 of
// 3072 f4; round-9 fixed the count but used global offset ph*48 f4 (= 8 p's)
// instead of ph*192 (= 32 p's) for the second k-half. One-constant fix.
// Structure: JT=16 (64B store runs), fp32 LDS weight staged in k-halves
// (48 KiB) with obuf OVERLAYING the dead weight buffer -> ~49 KiB LDS ->
// 3 blocks/CU = 24 waves/CU. Depth-1 x prefetch. BH=32, grid 2500,
// jt-major XCD swizzle (4 b-blocks of one j-tile share an XCD L2).

constexpr int B  = 128;
constexpr int M  = 10000;
constexpr int P  = 64;
constexpr int W  = 24;

constexpr int JT  = 16;   // j per block
constexpr int BH  = 32;   // b per block
constexpr int NT  = 512;  // 8 waves; wave k owns local j = k and k+8
constexpr int NWG = (M / JT) * (B / BH);  // 2500

__global__ __launch_bounds__(NT, 6) void pcl_kernel(
    const float* __restrict__ x, const float* __restrict__ wgt,
    const float* __restrict__ bias, float* __restrict__ out) {
  // wlds: [j 16][p_local 32][w 24] f32 = 49,152 B (one k-half).
  // obuf: [w 24][jl 16][bl 18] f32 = 27,648 B, overlays wlds after compute.
  __shared__ char smem[49152];
  float*  wlds = reinterpret_cast<float*>(smem);
  float4* wl4  = reinterpret_cast<float4*>(smem);
  float*  obuf = reinterpret_cast<float*>(smem);

  const int t = threadIdx.x;

  // bijective XCD swizzle (m204): 2500 = 8*312 + 4
  const int orig = blockIdx.x;
  const int xcd  = orig & 7;
  const int idx  = orig >> 3;
  const int wgid = (xcd < 4 ? xcd * 313 : 1252 + (xcd - 4) * 312) + idx;
  const int jt = wgid >> 2;   // 4 consecutive wgid = 4 b-blocks of one j-tile
  const int by = wgid & 3;
  const int j0 = jt * JT;
  const int b0 = by * BH;

  const int wk   = t >> 6;    // wave -> local j = wk, wk+8
  const int lane = t & 63;
  const int bl   = lane & 15; // b-lane
  const int wh   = lane >> 4; // w quarter
  const int w0   = 6 * wh;

  // bias -> acc[jj][bi][ww]
  float acc[2][2][6];
#pragma unroll
  for (int jj = 0; jj < 2; ++jj) {
    const float2* bp = reinterpret_cast<const float2*>(
        bias + (size_t)(j0 + wk + 8 * jj) * W + w0);
    const float2 bA = bp[0], bB = bp[1], bC = bp[2];
#pragma unroll
    for (int bi = 0; bi < 2; ++bi) {
      acc[jj][bi][0] = bA.x; acc[jj][bi][1] = bA.y;
      acc[jj][bi][2] = bB.x; acc[jj][bi][3] = bB.y;
      acc[jj][bi][4] = bC.x; acc[jj][bi][5] = bC.y;
    }
  }

  const float4* wg4 = reinterpret_cast<const float4*>(wgt);

#pragma unroll
  for (int ph = 0; ph < 2; ++ph) {
    if (ph) __syncthreads();  // prior half's wlds reads done before restage

    // ---- stage k-half: weight[j0:j0+16][ph*32:(ph+1)*32][:] -> 48 KiB ----
    // 3072 f4/half = 16 j x 192 f4. Global: j-row = 384 f4; half ph starts
    // at f4 offset ph*32p*6 = ph*192 within the row.
#pragma unroll
    for (int i = 0; i < 6; ++i) {
      const int s  = t + i * NT;      // 0..3071
      const int j  = s / 192;
      const int rr = s - j * 192;     // 0..191: p_local = rr/6, wq = rr%6
      wl4[s] = wg4[(size_t)(j0 + j) * (P * W / 4) + (size_t)ph * 192 + rr];
    }
    __syncthreads();  // staged visible

    // ---- compute this k-half: 2 j's, 8 chunks of 4 p, prefetch depth 1 ----
#pragma unroll
    for (int jj = 0; jj < 2; ++jj) {
      const int jl = wk + 8 * jj;
      const float4* xpa = reinterpret_cast<const float4*>(
          x + ((size_t)(b0 + bl) * M + j0 + jl) * P) + ph * 8;
      const float4* xpb = reinterpret_cast<const float4*>(
          x + ((size_t)(b0 + bl + 16) * M + j0 + jl) * P) + ph * 8;
      float4 xaN = xpa[0];
      float4 xbN = xpb[0];
#pragma unroll
      for (int c = 0; c < 8; ++c) {
        const float4 xa = xaN;
        const float4 xb = xbN;
        if (c < 7) { xaN = xpa[c + 1]; xbN = xpb[c + 1]; }
        const float* wbp = wlds + ((size_t)jl * 32 + 4 * c) * W + w0;
#pragma unroll
        for (int pp = 0; pp < 4; ++pp) {
          const float2* wp = reinterpret_cast<const float2*>(wbp + pp * W);
          const float2 wA = wp[0], wB = wp[1], wC = wp[2];
          const float xsa = pp == 0 ? xa.x : pp == 1 ? xa.y : pp == 2 ? xa.z : xa.w;
          const float xsb = pp == 0 ? xb.x : pp == 1 ? xb.y : pp == 2 ? xb.z : xb.w;
          acc[jj][0][0] = fmaf(xsa, wA.x, acc[jj][0][0]);
          acc[jj][0][1] = fmaf(xsa, wA.y, acc[jj][0][1]);
          acc[jj][0][2] = fmaf(xsa, wB.x, acc[jj][0][2]);
          acc[jj][0][3] = fmaf(xsa, wB.y, acc[jj][0][3]);
          acc[jj][0][4] = fmaf(xsa, wC.x, acc[jj][0][4]);
          acc[jj][0][5] = fmaf(xsa, wC.y, acc[jj][0][5]);
          acc[jj][1][0] = fmaf(xsb, wA.x, acc[jj][1][0]);
          acc[jj][1][1] = fmaf(xsb, wA.y, acc[jj][1][1]);
          acc[jj][1][2] = fmaf(xsb, wB.x, acc[jj][1][2]);
          acc[jj][1][3] = fmaf(xsb, wB.y, acc[jj][1][3]);
          acc[jj][1][4] = fmaf(xsb, wC.x, acc[jj][1][4]);
          acc[jj][1][5] = fmaf(xsb, wC.y, acc[jj][1][5]);
        }
      }
    }
  }

  // ---- stores: obuf overlays wlds; 2 rounds of 16 b; 64B j-runs ----
  __syncthreads();  // all wlds reads done before overlay
#pragma unroll
  for (int r = 0; r < 2; ++r) {
#pragma unroll
    for (int jj = 0; jj < 2; ++jj) {
      const int jl = wk + 8 * jj;
#pragma unroll
      for (int ww = 0; ww < 6; ++ww)
        obuf[((w0 + ww) * 16 + jl) * 18 + bl] = acc[jj][r][ww];
    }
    __syncthreads();  // obuf visible
#pragma unroll
    for (int it = 0; it < 3; ++it) {
      const int d   = t + it * NT;    // 0..1535
      const int jq  = d & 3;
      const int blr = (d >> 2) & 15;
      const int w   = d >> 6;         // 0..23
      float4 o;
      o.x = obuf[(w * 16 + 4 * jq + 0) * 18 + blr];
      o.y = obuf[(w * 16 + 4 * jq + 1) * 18 + blr];
      o.z = obuf[(w * 16 + 4 * jq + 2) * 18 + blr];
      o.w = obuf[(w * 16 + 4 * jq + 3) * 18 + blr];
      *reinterpret_cast<float4*>(
          out + ((size_t)(b0 + 16 * r + blr) * W + w) * M + j0 + 4 * jq) = o;
    }
    if (r == 0) __syncthreads();  // drain reads done before round-1 writes
  }
}

extern "C" void kernel_launch(void* const* d_in, const int* in_sizes, int n_in,
                              void* d_out, int out_size, void* d_ws, size_t ws_size,
                              hipStream_t stream) {
  const float* x    = (const float*)d_in[0];
  const float* wgt  = (const float*)d_in[1];
  const float* bias = (const float*)d_in[2];
  float* out        = (float*)d_out;

  dim3 grid(NWG);  // 2500
  dim3 block(NT);  // 512
  hipLaunchKernelGGL(pcl_kernel, grid, block, 0, stream, x, wgt, bias, out);
}

// Round 11
// 184.907 us; speedup vs baseline: 1.3937x; 1.3937x over previous
//
#include <hip/hip_runtime.h>

// out[b, w, j] = sum_p x[b,j,p] * weight[j,p,w] + bias[j,w]
// x: [B,M,P] f32, weight: [M,P,W] f32, bias: [M,W] f32, out: [B,W,M] f32
// B=128, M=10000, P=64, W=24. HBM floor ~475 MB (bf16 wgt) -> ~78 us.
//
// Round-11: round-10 structure minus its two taxes.
// (1) launch_bounds(512,4): this toolchain's allocator spills at min-waves=6
//     (rounds 3,10: VGPR 40 + ~115MB scratch writes). Occupancy comes from
//     resources anyway: LDS 49KB -> 3 blocks/CU when VGPR<=85.
// (2) weights bf16 in LDS [j][w][p] with 16B-chunk XOR swizzle -> full tile
//     is 49,152B (no k-half restaging), ds_read_b128 (8 p/read, ~2x LDS pipe
//     efficiency vs b32/b64), 4 wh-lanes on distinct banks, obuf overlays.
// Store path unchanged: obuf transpose, 64B j-runs, 2 rounds of 16 b.

constexpr int B  = 128;
constexpr int M  = 10000;
constexpr int P  = 64;
constexpr int W  = 24;

constexpr int JT  = 16;   // j per block
constexpr int BH  = 32;   // b per block
constexpr int NT  = 512;  // 8 waves; wave k owns local j = k and k+8
constexpr int NWG = (M / JT) * (B / BH);  // 2500

__device__ __forceinline__ float bf16lo(unsigned u) {
  return __uint_as_float(u << 16);
}
__device__ __forceinline__ float bf16hi(unsigned u) {
  return __uint_as_float(u & 0xffff0000u);
}

__global__ __launch_bounds__(NT, 4) void pcl_kernel(
    const float* __restrict__ x, const float* __restrict__ wgt,
    const float* __restrict__ bias, float* __restrict__ out) {
  // wsh: bf16 [j 16][w 24][p 64], p stored in 8-elem chunks at chunk index
  //      (p>>3)^(w&7)  -> 49,152 B. obuf (27,648 B) overlays after compute.
  __shared__ __align__(16) char smem[49152];
  unsigned short* wsh  = reinterpret_cast<unsigned short*>(smem);
  float*          obuf = reinterpret_cast<float*>(smem);

  const int t = threadIdx.x;

  // bijective XCD swizzle (m204): 2500 = 8*312 + 4
  const int orig = blockIdx.x;
  const int xcd  = orig & 7;
  const int idx  = orig >> 3;
  const int wgid = (xcd < 4 ? xcd * 313 : 1252 + (xcd - 4) * 312) + idx;
  const int jt = wgid >> 2;   // 4 consecutive wgid = 4 b-blocks of one j-tile
  const int by = wgid & 3;
  const int j0 = jt * JT;
  const int b0 = by * BH;

  // ---- stage weights -> bf16 LDS, transposed+swizzled ----
  {
    const float4* wg4 = reinterpret_cast<const float4*>(wgt);
#pragma unroll
    for (int i = 0; i < 12; ++i) {
      const int s  = t + i * NT;     // 0..6143 (16 j x 384 f4/j)
      const int j  = s / 384;
      const int rr = s - j * 384;    // p = rr/6, w4 = (rr%6)*4
      const int p  = rr / 6;
      const int w4 = (rr - 6 * p) * 4;
      const float4 v = wg4[(size_t)(j0 + j) * 384 + rr];
      const float vv[4] = {v.x, v.y, v.z, v.w};
#pragma unroll
      for (int k = 0; k < 4; ++k) {
        const int w = w4 + k;
        const unsigned u = __float_as_uint(vv[k]);
        const unsigned short h =
            (unsigned short)((u + 0x7fffu + ((u >> 16) & 1u)) >> 16);  // RNE
        wsh[((j * W + w) << 6) + (((p >> 3) ^ (w & 7)) << 3) + (p & 7)] = h;
      }
    }
  }

  const int wk   = t >> 6;    // wave -> local j = wk, wk+8
  const int lane = t & 63;
  const int bl   = lane & 15; // b-lane
  const int wh   = lane >> 4; // w quarter
  const int w0   = 6 * wh;

  // bias -> acc[jj][bi][ww]
  float acc[2][2][6];
#pragma unroll
  for (int jj = 0; jj < 2; ++jj) {
    const float2* bp = reinterpret_cast<const float2*>(
        bias + (size_t)(j0 + wk + 8 * jj) * W + w0);
    const float2 bA = bp[0], bB = bp[1], bC = bp[2];
#pragma unroll
    for (int bi = 0; bi < 2; ++bi) {
      acc[jj][bi][0] = bA.x; acc[jj][bi][1] = bA.y;
      acc[jj][bi][2] = bB.x; acc[jj][bi][3] = bB.y;
      acc[jj][bi][4] = bC.x; acc[jj][bi][5] = bC.y;
    }
  }

  __syncthreads();  // weights staged

  // ---- compute: per jj, 8 chunks of 8 p: 4 global f4 (x) + 6 ds_read_b128
  //      (weights, 8 p each) + 48 unpack + 96 FMA ----
#pragma unroll
  for (int jj = 0; jj < 2; ++jj) {
    const int jl = wk + 8 * jj;
    const float4* xpa = reinterpret_cast<const float4*>(
        x + ((size_t)(b0 + bl) * M + j0 + jl) * P);
    const float4* xpb = reinterpret_cast<const float4*>(
        x + ((size_t)(b0 + bl + 16) * M + j0 + jl) * P);
#pragma unroll 2
    for (int cc = 0; cc < 8; ++cc) {
      const float4 a0 = xpa[2 * cc], a1 = xpa[2 * cc + 1];
      const float4 c0 = xpb[2 * cc], c1 = xpb[2 * cc + 1];
      const float xa[8] = {a0.x, a0.y, a0.z, a0.w, a1.x, a1.y, a1.z, a1.w};
      const float xb[8] = {c0.x, c0.y, c0.z, c0.w, c1.x, c1.y, c1.z, c1.w};
#pragma unroll
      for (int ww = 0; ww < 6; ++ww) {
        const int w = w0 + ww;
        const uint4 u = *reinterpret_cast<const uint4*>(
            wsh + ((jl * W + w) << 6) + ((cc ^ (w & 7)) << 3));
        const float pw[8] = {bf16lo(u.x), bf16hi(u.x), bf16lo(u.y),
                             bf16hi(u.y), bf16lo(u.z), bf16hi(u.z),
                             bf16lo(u.w), bf16hi(u.w)};
#pragma unroll
        for (int e = 0; e < 8; ++e) {
          acc[jj][0][ww] = fmaf(xa[e], pw[e], acc[jj][0][ww]);
          acc[jj][1][ww] = fmaf(xb[e], pw[e], acc[jj][1][ww]);
        }
      }
    }
  }

  // ---- stores: obuf overlays wsh; 2 rounds of 16 b; 64B j-runs ----
  __syncthreads();  // all wsh reads done before overlay
#pragma unroll
  for (int r = 0; r < 2; ++r) {
#pragma unroll
    for (int jj = 0; jj < 2; ++jj) {
      const int jl = wk + 8 * jj;
#pragma unroll
      for (int ww = 0; ww < 6; ++ww)
        obuf[((w0 + ww) * 16 + jl) * 18 + bl] = acc[jj][r][ww];
    }
    __syncthreads();  // obuf visible
#pragma unroll
    for (int it = 0; it < 3; ++it) {
      const int d   = t + it * NT;    // 0..1535
      const int jq  = d & 3;
      const int blr = (d >> 2) & 15;
      const int w   = d >> 6;         // 0..23
      float4 o;
      o.x = obuf[(w * 16 + 4 * jq + 0) * 18 + blr];
      o.y = obuf[(w * 16 + 4 * jq + 1) * 18 + blr];
      o.z = obuf[(w * 16 + 4 * jq + 2) * 18 + blr];
      o.w = obuf[(w * 16 + 4 * jq + 3) * 18 + blr];
      *reinterpret_cast<float4*>(
          out + ((size_t)(b0 + 16 * r + blr) * W + w) * M + j0 + 4 * jq) = o;
    }
    if (r == 0) __syncthreads();  // drain reads done before round-1 writes
  }
}

extern "C" void kernel_launch(void* const* d_in, const int* in_sizes, int n_in,
                              void* d_out, int out_size, void* d_ws, size_t ws_size,
                              hipStream_t stream) {
  const float* x    = (const float*)d_in[0];
  const float* wgt  = (const float*)d_in[1];
  const float* bias = (const float*)d_in[2];
  float* out        = (float*)d_out;

  dim3 grid(NWG);  // 2500
  dim3 block(NT);  // 512
  hipLaunchKernelGGL(pcl_kernel, grid, block, 0, stream, x, wgt, bias, out);
}

// Round 12
// 130.097 us; speedup vs baseline: 1.9809x; 1.4213x over previous
//
#include <hip/hip_runtime.h>

// out[b, w, j] = sum_p x[b,j,p] * weight[j,p,w] + bias[j,w]
// x: [B,M,P] f32, weight: [M,P,W] f32, bias: [M,W] f32, out: [B,W,M] f32
// B=128, M=10000, P=64, W=24.
//
// Round-12: per-j GEMM (128x64)x(64x24) on MFMA (mfma_f32_16x16x32_bf16),
// removing round-11's VALU bottleneck (40% busy, ~2300 instr/thread scalar
// FMA+unpack). Round-11 skeleton kept: grid 2500 + XCD swizzle, bf16 weight
// staging verbatim ([j][w][p] chunk-XOR = exactly MFMA B-frag order: lane
// col=l&15 -> w, 8 contiguous p -> one ds_read_b128, no unpack). A-frags
// from global (2 float4 + 8 bf16 casts/lane). C-layout (m89): col=lane&15,
// row=(lane>>4)*4+reg -> obuf [j][b][w+pad] transpose -> 64B j-run stores.

constexpr int B  = 128;
constexpr int M  = 10000;
constexpr int P  = 64;
constexpr int W  = 24;

constexpr int JT  = 16;   // j per block; wave k owns local j = k, k+8
constexpr int BH  = 32;   // b per block (2 M-tiles)
constexpr int NT  = 512;  // 8 waves
constexpr int NWG = (M / JT) * (B / BH);  // 2500

using bf8   = __attribute__((ext_vector_type(8))) __bf16;
using f32x4 = __attribute__((ext_vector_type(4))) float;

__global__ __launch_bounds__(NT, 4) void pcl_kernel(
    const float* __restrict__ x, const float* __restrict__ wgt,
    const float* __restrict__ bias, float* __restrict__ out) {
  // wsh: bf16 [j 16][w 24][p 64], p in 8-chunks at chunk idx (p>>3)^(w&7).
  // obuf: f32 [j*16+b][w 25pad] = 25,600 B, overlays wsh after compute.
  __shared__ __align__(16) char smem[49152];
  unsigned short* wsh  = reinterpret_cast<unsigned short*>(smem);
  float*          obuf = reinterpret_cast<float*>(smem);

  const int t = threadIdx.x;

  // bijective XCD swizzle (m204): 2500 = 8*312 + 4
  const int orig = blockIdx.x;
  const int xcd  = orig & 7;
  const int idx  = orig >> 3;
  const int wgid = (xcd < 4 ? xcd * 313 : 1252 + (xcd - 4) * 312) + idx;
  const int jt = wgid >> 2;
  const int by = wgid & 3;
  const int j0 = jt * JT;
  const int b0 = by * BH;

  // ---- stage weights -> bf16 LDS (verbatim round-11, proven) ----
  {
    const float4* wg4 = reinterpret_cast<const float4*>(wgt);
#pragma unroll
    for (int i = 0; i < 12; ++i) {
      const int s  = t + i * NT;     // 0..6143 (16 j x 384 f4/j)
      const int j  = s / 384;
      const int rr = s - j * 384;
      const int p  = rr / 6;
      const int w4 = (rr - 6 * p) * 4;
      const float4 v = wg4[(size_t)(j0 + j) * 384 + rr];
      const float vv[4] = {v.x, v.y, v.z, v.w};
#pragma unroll
      for (int k = 0; k < 4; ++k) {
        const int w = w4 + k;
        const unsigned u = __float_as_uint(vv[k]);
        const unsigned short h =
            (unsigned short)((u + 0x7fffu + ((u >> 16) & 1u)) >> 16);  // RNE
        wsh[((j * W + w) << 6) + (((p >> 3) ^ (w & 7)) << 3) + (p & 7)] = h;
      }
    }
  }

  const int wk   = t >> 6;
  const int lane = t & 63;
  const int col  = lane & 15;  // MFMA: A-row / B-col / D-col
  const int kg   = lane >> 4;  // k-group: k = kg*8 + e (per K-step)

  // acc[jj][mt][nt] initialized with bias (D col = w, same for all rows)
  f32x4 acc[2][2][2];
#pragma unroll
  for (int jj = 0; jj < 2; ++jj) {
    const int j = j0 + wk + 8 * jj;
#pragma unroll
    for (int nt = 0; nt < 2; ++nt) {
      const int w  = nt * 16 + col;
      const float bv = (w < W) ? bias[(size_t)j * W + w] : 0.0f;
#pragma unroll
      for (int mt = 0; mt < 2; ++mt) acc[jj][mt][nt] = f32x4{bv, bv, bv, bv};
    }
  }

  __syncthreads();  // weights staged

  // ---- compute: per (jj, ks): 4 global f4 + 8 casts, 2 ds_read_b128,
  //      4 MFMA.  16 MFMA per wave total. ----
#pragma unroll
  for (int jj = 0; jj < 2; ++jj) {
    const int jl = wk + 8 * jj;
    const int j  = j0 + jl;
#pragma unroll
    for (int ks = 0; ks < 2; ++ks) {
      bf8 af[2];
#pragma unroll
      for (int mt = 0; mt < 2; ++mt) {
        const float* xr =
            x + ((size_t)(b0 + mt * 16 + col) * M + j) * P + ks * 32 + kg * 8;
        const float4 u0 = *reinterpret_cast<const float4*>(xr);
        const float4 u1 = *reinterpret_cast<const float4*>(xr + 4);
        af[mt][0] = (__bf16)u0.x; af[mt][1] = (__bf16)u0.y;
        af[mt][2] = (__bf16)u0.z; af[mt][3] = (__bf16)u0.w;
        af[mt][4] = (__bf16)u1.x; af[mt][5] = (__bf16)u1.y;
        af[mt][6] = (__bf16)u1.z; af[mt][7] = (__bf16)u1.w;
      }
      bf8 bfr[2];
#pragma unroll
      for (int nt = 0; nt < 2; ++nt) {
        const int w  = nt * 16 + col;
        const int wr = (w < W) ? w : 0;
        const int c  = ks * 4 + kg;
        bf8 v = *reinterpret_cast<const bf8*>(
            wsh + ((jl * W + wr) << 6) + ((c ^ (wr & 7)) << 3));
        if (w >= W) {
#pragma unroll
          for (int e = 0; e < 8; ++e) v[e] = (__bf16)0.0f;
        }
        bfr[nt] = v;
      }
#pragma unroll
      for (int mt = 0; mt < 2; ++mt)
#pragma unroll
        for (int nt = 0; nt < 2; ++nt)
          acc[jj][mt][nt] = __builtin_amdgcn_mfma_f32_16x16x32_bf16(
              af[mt], bfr[nt], acc[jj][mt][nt], 0, 0, 0);
    }
  }

  // ---- stores: obuf [j*16+b][25] overlays wsh; 2 rounds (mt); 64B j-runs --
  __syncthreads();  // all wsh reads done
#pragma unroll
  for (int r = 0; r < 2; ++r) {
#pragma unroll
    for (int jj = 0; jj < 2; ++jj) {
      const int jl = wk + 8 * jj;
#pragma unroll
      for (int nt = 0; nt < 2; ++nt) {
        const int w = nt * 16 + col;
        if (w < W) {
#pragma unroll
          for (int reg = 0; reg < 4; ++reg) {
            const int brow = kg * 4 + reg;  // D row = b within 16-tile
            obuf[(jl * 16 + brow) * 25 + w] = acc[jj][r][nt][reg];
          }
        }
      }
    }
    __syncthreads();  // obuf visible
#pragma unroll
    for (int it = 0; it < 3; ++it) {
      const int d    = t + it * NT;   // 0..1535
      const int jq   = d & 3;
      const int rest = d >> 2;        // 0..383
      const int w    = rest % 24;
      const int br   = rest / 24;     // 0..15
      float4 o;
      o.x = obuf[((4 * jq + 0) * 16 + br) * 25 + w];
      o.y = obuf[((4 * jq + 1) * 16 + br) * 25 + w];
      o.z = obuf[((4 * jq + 2) * 16 + br) * 25 + w];
      o.w = obuf[((4 * jq + 3) * 16 + br) * 25 + w];
      *reinterpret_cast<float4*>(
          out + ((size_t)(b0 + r * 16 + br) * W + w) * M + j0 + 4 * jq) = o;
    }
    if (r == 0) __syncthreads();  // drain reads done before round-1 writes
  }
}

extern "C" void kernel_launch(void* const* d_in, const int* in_sizes, int n_in,
                              void* d_out, int out_size, void* d_ws, size_t ws_size,
                              hipStream_t stream) {
  const float* x    = (const float*)d_in[0];
  const float* wgt  = (const float*)d_in[1];
  const float* bias = (const float*)d_in[2];
  float* out        = (float*)d_out;

  dim3 grid(NWG);  // 2500
  dim3 block(NT);  // 512
  hipLaunchKernelGGL(pcl_kernel, grid, block, 0, stream, x, wgt, bias, out);
}

// Round 13
// 125.559 us; speedup vs baseline: 2.0525x; 1.0361x over previous
//
#include <hip/hip_runtime.h>

// out[b, w, j] = sum_p x[b,j,p] * weight[j,p,w] + bias[j,w]
// x: [B,M,P] f32, weight: [M,P,W] f32, bias: [M,W] f32, out: [B,W,M] f32
// B=128, M=10000, P=64, W=24.
//
// Round-13: round-12 MFMA kernel with x routed through LDS. The A-frag
// global loads (16 scattered b-rows / instr) capped HBM at ~2.6 TB/s in
// every per-lane-row variant (r5/r6/r12). x[b, j0:j0+16, :] is 4KB
// contiguous -> stage via regs (1KB/wave coalesced), convert bf16 once,
// ds_write_b64 into chunk-XOR slab; A-frags become conflict-free
// ds_read_b128 (8 lanes/bank-quad via s = c ^ (b&7), matching weights).
// BH=16, grid 5000 = 8*625: 8 consecutive wgid = 8 b-blocks of one jt on
// one XCD -> weight from L2. LDS 48K wsh + 32K xsh = 80KB -> 2 blocks/CU.

constexpr int B  = 128;
constexpr int M  = 10000;
constexpr int P  = 64;
constexpr int W  = 24;

constexpr int JT  = 16;   // j per block; wave k owns local j = k, k+8
constexpr int BH  = 16;   // b per block (one M-tile)
constexpr int NT  = 512;  // 8 waves
constexpr int NWG = (M / JT) * (B / BH);  // 625*8 = 5000

using bf8   = __attribute__((ext_vector_type(8))) __bf16;
using f32x4 = __attribute__((ext_vector_type(4))) float;

__device__ __forceinline__ unsigned short rne_bf16(float f) {
  const unsigned u = __float_as_uint(f);
  return (unsigned short)((u + 0x7fffu + ((u >> 16) & 1u)) >> 16);
}

__global__ __launch_bounds__(NT, 4) void pcl_kernel(
    const float* __restrict__ x, const float* __restrict__ wgt,
    const float* __restrict__ bias, float* __restrict__ out) {
  // wsh: bf16 [j 16][w 24][p 64], p-chunks (8 p = 16B) at idx (p>>3)^(w&7).
  // xsh: bf16 [b 16][j 16][p 64], p-chunks at idx (p>>3)^(b&7).
  // obuf: f32 [jl*16+b][w 25pad] = 25,600 B, overlays wsh after compute.
  __shared__ __align__(16) char smem[81920];
  unsigned short* wsh  = reinterpret_cast<unsigned short*>(smem);
  unsigned short* xsh  = reinterpret_cast<unsigned short*>(smem + 49152);
  float*          obuf = reinterpret_cast<float*>(smem);

  const int t = threadIdx.x;

  // XCD swizzle (5000 % 8 == 0): XCD k gets wgid [625k, 625k+625);
  // consecutive wgid on an XCD share jt (8 b-blocks -> weight L2 reuse).
  const int orig = blockIdx.x;
  const int wgid = (orig & 7) * (NWG / 8) + (orig >> 3);
  const int jt = wgid >> 3;
  const int by = wgid & 7;
  const int j0 = jt * JT;
  const int b0 = by * BH;

  // ---- stage weights -> bf16 LDS (r11/r12 verbatim, proven) ----
  {
    const float4* wg4 = reinterpret_cast<const float4*>(wgt);
#pragma unroll
    for (int i = 0; i < 12; ++i) {
      const int s  = t + i * NT;     // 0..6143 (16 j x 384 f4/j)
      const int j  = s / 384;
      const int rr = s - j * 384;
      const int p  = rr / 6;
      const int w4 = (rr - 6 * p) * 4;
      const float4 v = wg4[(size_t)(j0 + j) * 384 + rr];
      const float vv[4] = {v.x, v.y, v.z, v.w};
#pragma unroll
      for (int k = 0; k < 4; ++k) {
        const int w = w4 + k;
        wsh[((j * W + w) << 6) + (((p >> 3) ^ (w & 7)) << 3) + (p & 7)] =
            rne_bf16(vv[k]);
      }
    }
  }

  // ---- stage x -> bf16 LDS, chunk-swizzled; reads fully coalesced ----
  {
#pragma unroll
    for (int i = 0; i < 8; ++i) {
      const int g   = t + i * NT;   // 0..4095 f4 over [b 16][j 16][p-f4 16]
      const int b   = g >> 8;
      const int rem = g & 255;
      const int j   = rem >> 4;
      const int c2  = rem & 15;     // fp32 16B-chunk (4 p)
      const float4 v = *reinterpret_cast<const float4*>(
          x + ((size_t)(b0 + b) * M + j0 + j) * P + 4 * c2);
      const unsigned u0 = (unsigned)rne_bf16(v.x) | ((unsigned)rne_bf16(v.y) << 16);
      const unsigned u1 = (unsigned)rne_bf16(v.z) | ((unsigned)rne_bf16(v.w) << 16);
      const int s = (c2 >> 1) ^ (b & 7);   // bf16 chunk (8 p) swizzle
      uint2* dst = reinterpret_cast<uint2*>(
          xsh + (((b << 4) + j) << 6) + (s << 3) + ((c2 & 1) << 2));
      *dst = uint2{u0, u1};
    }
  }

  const int wk   = t >> 6;
  const int lane = t & 63;
  const int col  = lane & 15;  // A-row(b) / B-col(w) / D-col(w)
  const int kg   = lane >> 4;  // k-group

  // acc[jj][nt] init with bias
  f32x4 acc[2][2];
#pragma unroll
  for (int jj = 0; jj < 2; ++jj) {
    const int j = j0 + wk + 8 * jj;
#pragma unroll
    for (int nt = 0; nt < 2; ++nt) {
      const int w = nt * 16 + col;
      const float bv = (w < W) ? bias[(size_t)j * W + w] : 0.0f;
      acc[jj][nt] = f32x4{bv, bv, bv, bv};
    }
  }

  __syncthreads();  // both stages visible

  // ---- compute: per (jj, ks): 1 A ds_read_b128 + 2 B ds_read_b128 + 2 MFMA
#pragma unroll
  for (int jj = 0; jj < 2; ++jj) {
    const int jl = wk + 8 * jj;
#pragma unroll
    for (int ks = 0; ks < 2; ++ks) {
      const int c = ks * 4 + kg;
      const bf8 af = *reinterpret_cast<const bf8*>(
          xsh + (((col << 4) + jl) << 6) + ((c ^ (col & 7)) << 3));
      bf8 bfr[2];
#pragma unroll
      for (int nt = 0; nt < 2; ++nt) {
        const int w  = nt * 16 + col;
        const int wr = (w < W) ? w : 0;
        bf8 v = *reinterpret_cast<const bf8*>(
            wsh + ((jl * W + wr) << 6) + ((c ^ (wr & 7)) << 3));
        if (w >= W) {
#pragma unroll
          for (int e = 0; e < 8; ++e) v[e] = (__bf16)0.0f;
        }
        bfr[nt] = v;
      }
#pragma unroll
      for (int nt = 0; nt < 2; ++nt)
        acc[jj][nt] = __builtin_amdgcn_mfma_f32_16x16x32_bf16(
            af, bfr[nt], acc[jj][nt], 0, 0, 0);
    }
  }

  // ---- store: obuf overlays wsh; single round (16 b); 64B j-runs ----
  __syncthreads();  // all wsh/xsh reads done
#pragma unroll
  for (int jj = 0; jj < 2; ++jj) {
    const int jl = wk + 8 * jj;
#pragma unroll
    for (int nt = 0; nt < 2; ++nt) {
      const int w = nt * 16 + col;
      if (w < W) {
#pragma unroll
        for (int reg = 0; reg < 4; ++reg) {
          const int brow = kg * 4 + reg;  // D row = b within 16-tile
          obuf[(jl * 16 + brow) * 25 + w] = acc[jj][nt][reg];
        }
      }
    }
  }
  __syncthreads();  // obuf visible
#pragma unroll
  for (int it = 0; it < 3; ++it) {
    const int d    = t + it * NT;   // 0..1535
    const int jq   = d & 3;
    const int rest = d >> 2;        // 0..383
    const int w    = rest % 24;
    const int br   = rest / 24;     // 0..15
    float4 o;
    o.x = obuf[((4 * jq + 0) * 16 + br) * 25 + w];
    o.y = obuf[((4 * jq + 1) * 16 + br) * 25 + w];
    o.z = obuf[((4 * jq + 2) * 16 + br) * 25 + w];
    o.w = obuf[((4 * jq + 3) * 16 + br) * 25 + w];
    *reinterpret_cast<float4*>(
        out + ((size_t)(b0 + br) * W + w) * M + j0 + 4 * jq) = o;
  }
}

extern "C" void kernel_launch(void* const* d_in, const int* in_sizes, int n_in,
                              void* d_out, int out_size, void* d_ws, size_t ws_size,
                              hipStream_t stream) {
  const float* x    = (const float*)d_in[0];
  const float* wgt  = (const float*)d_in[1];
  const float* bias = (const float*)d_in[2];
  float* out        = (float*)d_out;

  dim3 grid(NWG);  // 5000
  dim3 block(NT);  // 512
  hipLaunchKernelGGL(pcl_kernel, grid, block, 0, stream, x, wgt, bias, out);
}

// Round 14
// 119.619 us; speedup vs baseline: 2.1544x; 1.0497x over previous
//
#include <hip/hip_runtime.h>

// out[b, w, j] = sum_p x[b,j,p] * weight[j,p,w] + bias[j,w]
// x: [B,M,P] f32, weight: [M,P,W] f32, bias: [M,W] f32, out: [B,W,M] f32
// B=128, M=10000, P=64, W=24.
//
// Round-14: r13 MFMA datapath verbatim; block restructured to one jt x 64 b
// in 4 chunks of 16. Weight staged ONCE per block (was 8x per jt over the
// grid). x chunk c+1 prefetched to 8 float4 regs before chunk c's compute
// (T14: global latency hides under compute+store). obuf overlays the xsh
// region (wsh persists across chunks); next chunk's xsh write fully covers
// obuf after the drain barrier. LDS 48K wsh + 32K (xsh|obuf) = 80 KB ->
// 2 blocks/CU. Grid 1250, m204 bijective XCD swizzle, jt-pair locality.

constexpr int B  = 128;
constexpr int M  = 10000;
constexpr int P  = 64;
constexpr int W  = 24;

constexpr int JT  = 16;   // j per block; wave k owns local j = k, k+8
constexpr int BH  = 16;   // b per chunk (one M-tile)
constexpr int NCH = 4;    // chunks per block -> 64 b per block
constexpr int NT  = 512;  // 8 waves
constexpr int NWG = (M / JT) * (B / (BH * NCH));  // 625*2 = 1250

using bf8   = __attribute__((ext_vector_type(8))) __bf16;
using f32x4 = __attribute__((ext_vector_type(4))) float;

__device__ __forceinline__ unsigned short rne_bf16(float f) {
  const unsigned u = __float_as_uint(f);
  return (unsigned short)((u + 0x7fffu + ((u >> 16) & 1u)) >> 16);
}

__global__ __launch_bounds__(NT, 4) void pcl_kernel(
    const float* __restrict__ x, const float* __restrict__ wgt,
    const float* __restrict__ bias, float* __restrict__ out) {
  // wsh: bf16 [j 16][w 24][p 64], p-chunks (8 p = 16B) at idx (p>>3)^(w&7).
  // xsh: bf16 [b 16][j 16][p 64], p-chunks at idx (p>>3)^(b&7)  (32,768 B).
  // obuf: f32 [jl*16+b][w 25pad] = 25,600 B, OVERLAYS xsh between chunks.
  __shared__ __align__(16) char smem[81920];
  unsigned short* wsh  = reinterpret_cast<unsigned short*>(smem);
  unsigned short* xsh  = reinterpret_cast<unsigned short*>(smem + 49152);
  float*          obuf = reinterpret_cast<float*>(smem + 49152);

  const int t = threadIdx.x;

  // bijective XCD swizzle (m204): 1250 = 8*156 + 2; consecutive wgid on one
  // XCD share jt (2 b-halves) -> weight L2 reuse.
  const int orig = blockIdx.x;
  const int xcd  = orig & 7;
  const int idx  = orig >> 3;
  const int wgid = (xcd < 2 ? xcd * 157 : 314 + (xcd - 2) * 156) + idx;
  const int jt    = wgid >> 1;
  const int bbase = (wgid & 1) * (BH * NCH);  // 0 or 64
  const int j0    = jt * JT;

  const int wk   = t >> 6;
  const int lane = t & 63;
  const int col  = lane & 15;  // A-row(b) / B-col(w) / D-col(w)
  const int kg   = lane >> 4;  // k-group

  // hoisted bias values (per-lane)
  float bv[2][2];
#pragma unroll
  for (int jj = 0; jj < 2; ++jj) {
    const int j = j0 + wk + 8 * jj;
#pragma unroll
    for (int nt = 0; nt < 2; ++nt) {
      const int w = nt * 16 + col;
      bv[jj][nt] = (w < W) ? bias[(size_t)j * W + w] : 0.0f;
    }
  }

  // ---- prefetch x chunk 0 into regs (8 f4/thread = full 32KB chunk) ----
  float4 nx[8];
#pragma unroll
  for (int i = 0; i < 8; ++i) {
    const int g   = t + i * NT;   // [b 16][j 16][p-f4 16]
    const int b   = g >> 8;
    const int j   = (g >> 4) & 15;
    const int c2  = g & 15;
    nx[i] = *reinterpret_cast<const float4*>(
        x + ((size_t)(bbase + b) * M + j0 + j) * P + 4 * c2);
  }

  // ---- stage weights -> bf16 LDS (r11-r13 verbatim, proven) ----
  {
    const float4* wg4 = reinterpret_cast<const float4*>(wgt);
#pragma unroll
    for (int i = 0; i < 12; ++i) {
      const int s  = t + i * NT;     // 0..6143 (16 j x 384 f4/j)
      const int j  = s / 384;
      const int rr = s - j * 384;
      const int p  = rr / 6;
      const int w4 = (rr - 6 * p) * 4;
      const float4 v = wg4[(size_t)(j0 + j) * 384 + rr];
      const float vv[4] = {v.x, v.y, v.z, v.w};
#pragma unroll
      for (int k = 0; k < 4; ++k) {
        const int w = w4 + k;
        wsh[((j * W + w) << 6) + (((p >> 3) ^ (w & 7)) << 3) + (p & 7)] =
            rne_bf16(vv[k]);
      }
    }
  }

  for (int c = 0; c < NCH; ++c) {
    if (c > 0) __syncthreads();  // obuf drain reads done -> xsh region free

    // ---- convert + write chunk c from regs into swizzled xsh ----
#pragma unroll
    for (int i = 0; i < 8; ++i) {
      const int g  = t + i * NT;
      const int b  = g >> 8;
      const int j  = (g >> 4) & 15;
      const int c2 = g & 15;
      const unsigned u0 =
          (unsigned)rne_bf16(nx[i].x) | ((unsigned)rne_bf16(nx[i].y) << 16);
      const unsigned u1 =
          (unsigned)rne_bf16(nx[i].z) | ((unsigned)rne_bf16(nx[i].w) << 16);
      const int s = (c2 >> 1) ^ (b & 7);
      *reinterpret_cast<uint2*>(xsh + (((b << 4) + j) << 6) + (s << 3) +
                                ((c2 & 1) << 2)) = uint2{u0, u1};
    }

    // ---- issue chunk c+1 global loads (land during compute/store) ----
    if (c < NCH - 1) {
      const int b0n = bbase + (c + 1) * BH;
#pragma unroll
      for (int i = 0; i < 8; ++i) {
        const int g   = t + i * NT;
        const int b   = g >> 8;
        const int j   = (g >> 4) & 15;
        const int c2  = g & 15;
        nx[i] = *reinterpret_cast<const float4*>(
            x + ((size_t)(b0n + b) * M + j0 + j) * P + 4 * c2);
      }
    }

    __syncthreads();  // xsh (and wsh on first iter) visible

    // ---- compute: per (jj, ks): 1 A + 2 B ds_read_b128, 2 MFMA ----
    f32x4 acc[2][2];
#pragma unroll
    for (int jj = 0; jj < 2; ++jj)
#pragma unroll
      for (int nt = 0; nt < 2; ++nt)
        acc[jj][nt] = f32x4{bv[jj][nt], bv[jj][nt], bv[jj][nt], bv[jj][nt]};

#pragma unroll
    for (int jj = 0; jj < 2; ++jj) {
      const int jl = wk + 8 * jj;
#pragma unroll
      for (int ks = 0; ks < 2; ++ks) {
        const int cc = ks * 4 + kg;
        const bf8 af = *reinterpret_cast<const bf8*>(
            xsh + (((col << 4) + jl) << 6) + ((cc ^ (col & 7)) << 3));
        bf8 bfr[2];
#pragma unroll
        for (int nt = 0; nt < 2; ++nt) {
          const int w  = nt * 16 + col;
          const int wr = (w < W) ? w : 0;
          bf8 v = *reinterpret_cast<const bf8*>(
              wsh + ((jl * W + wr) << 6) + ((cc ^ (wr & 7)) << 3));
          if (w >= W) {
#pragma unroll
            for (int e = 0; e < 8; ++e) v[e] = (__bf16)0.0f;
          }
          bfr[nt] = v;
        }
#pragma unroll
        for (int nt = 0; nt < 2; ++nt)
          acc[jj][nt] = __builtin_amdgcn_mfma_f32_16x16x32_bf16(
              af, bfr[nt], acc[jj][nt], 0, 0, 0);
      }
    }

    __syncthreads();  // compute's xsh reads done before obuf overlay write

    // ---- obuf transpose write ----
#pragma unroll
    for (int jj = 0; jj < 2; ++jj) {
      const int jl = wk + 8 * jj;
#pragma unroll
      for (int nt = 0; nt < 2; ++nt) {
        const int w = nt * 16 + col;
        if (w < W) {
#pragma unroll
          for (int reg = 0; reg < 4; ++reg)
            obuf[(jl * 16 + kg * 4 + reg) * 25 + w] = acc[jj][nt][reg];
        }
      }
    }
    __syncthreads();  // obuf visible

    // ---- drain: 64B j-run float4 stores ----
    const int b0c = bbase + c * BH;
#pragma unroll
    for (int it = 0; it < 3; ++it) {
      const int d    = t + it * NT;   // 0..1535
      const int jq   = d & 3;
      const int rest = d >> 2;        // 0..383
      const int w    = rest % 24;
      const int br   = rest / 24;     // 0..15
      float4 o;
      o.x = obuf[((4 * jq + 0) * 16 + br) * 25 + w];
      o.y = obuf[((4 * jq + 1) * 16 + br) * 25 + w];
      o.z = obuf[((4 * jq + 2) * 16 + br) * 25 + w];
      o.w = obuf[((4 * jq + 3) * 16 + br) * 25 + w];
      *reinterpret_cast<float4*>(
          out + ((size_t)(b0c + br) * W + w) * M + j0 + 4 * jq) = o;
    }
  }
}

extern "C" void kernel_launch(void* const* d_in, const int* in_sizes, int n_in,
                              void* d_out, int out_size, void* d_ws, size_t ws_size,
                              hipStream_t stream) {
  const float* x    = (const float*)d_in[0];
  const float* wgt  = (const float*)d_in[1];
  const float* bias = (const float*)d_in[2];
  float* out        = (float*)d_out;

  dim3 grid(NWG);  // 1250
  dim3 block(NT);  // 512
  hipLaunchKernelGGL(pcl_kernel, grid, block, 0, stream, x, wgt, bias, out);
}

// Round 15
// 111.801 us; speedup vs baseline: 2.3050x; 1.0699x over previous
//
#include <hip/hip_runtime.h>

// out[b, w, j] = sum_p x[b,j,p] * weight[j,p,w] + bias[j,w]
// x: [B,M,P] f32, weight: [M,P,W] f32, bias: [M,W] f32, out: [B,W,M] f32
// B=128, M=10000, P=64, W=24.
//
// Round-15: NT=1024, ONE j per wave -> per-lane weight B-frags fit in 16
// VGPRs; wsh (48K LDS + staging conflicts + 16 ds_read/chunk) deleted.
// LDS = 32K xsh only (obuf overlays) -> occupancy limited by VGPR alone;
// live set ~60 -> target 64 VGPR -> 8 waves/SIMD = 32 waves/CU (2x r14's
// latency hiding). x path / MFMA mapping / obuf transpose / 64B j-run
// stores are r13/14 verbatim. Weight: 32 scattered dwords/lane once per
// block (4x64B segs/instr), L2-served on the jt-paired block.

constexpr int B  = 128;
constexpr int M  = 10000;
constexpr int P  = 64;
constexpr int W  = 24;

constexpr int JT  = 16;    // j per block = waves per block
constexpr int BH  = 16;    // b per chunk (one M-tile)
constexpr int NCH = 4;     // chunks per block -> 64 b per block
constexpr int NT  = 1024;  // 16 waves
constexpr int NWG = (M / JT) * (B / (BH * NCH));  // 1250

using bf8   = __attribute__((ext_vector_type(8))) __bf16;
using bf4   = __attribute__((ext_vector_type(4))) __bf16;
using f32x4 = __attribute__((ext_vector_type(4))) float;

__global__ __launch_bounds__(NT, 4) void pcl_kernel(
    const float* __restrict__ x, const float* __restrict__ wgt,
    const float* __restrict__ bias, float* __restrict__ out) {
  // xsh: bf16 [b 16][j 16][p 64], p-chunks (8 p = 16B) at idx (p>>3)^(b&7).
  // obuf: f32 [jl*16+b][w 25pad] = 25,600 B, overlays xsh between chunks.
  __shared__ __align__(16) char smem[32768];
  unsigned short* xsh  = reinterpret_cast<unsigned short*>(smem);
  float*          obuf = reinterpret_cast<float*>(smem);

  const int t = threadIdx.x;

  // bijective XCD swizzle (m204): 1250 = 8*156 + 2; consecutive wgid on one
  // XCD share jt (2 b-halves) -> weight L2 reuse.
  const int orig = blockIdx.x;
  const int xcd  = orig & 7;
  const int idx  = orig >> 3;
  const int wgid = (xcd < 2 ? xcd * 157 : 314 + (xcd - 2) * 156) + idx;
  const int jt    = wgid >> 1;
  const int bbase = (wgid & 1) * (BH * NCH);  // 0 or 64
  const int j0    = jt * JT;

  const int wk   = t >> 6;     // wave = local j
  const int lane = t & 63;
  const int col  = lane & 15;  // A-row(b) / B-col(w) / D-col(w)
  const int kg   = lane >> 4;  // k-group
  const int j    = j0 + wk;    // this wave's j

  // bias (per-lane, hoisted)
  float bv[2];
#pragma unroll
  for (int nt = 0; nt < 2; ++nt) {
    const int w = nt * 16 + col;
    bv[nt] = (w < W) ? bias[(size_t)j * W + w] : 0.0f;
  }

  // ---- weight B-frags -> 16 VGPRs (once per block) ----
  bf8 bfr[2][2];
#pragma unroll
  for (int ks = 0; ks < 2; ++ks) {
#pragma unroll
    for (int nt = 0; nt < 2; ++nt) {
      const int w     = nt * 16 + col;
      const bool ok   = (w < W);
      const float* wp = wgt + (size_t)j * (P * W) +
                        (size_t)(ks * 32 + kg * 8) * W + (ok ? w : 0);
      bf8 v;
#pragma unroll
      for (int e = 0; e < 8; ++e) v[e] = (__bf16)wp[(size_t)e * W];
      if (!ok) {
#pragma unroll
        for (int e = 0; e < 8; ++e) v[e] = (__bf16)0.0f;
      }
      bfr[ks][nt] = v;
    }
  }

  // ---- prefetch x chunk 0 (4 f4/thread = 16 VGPR; 1KB/instr contiguous) --
  float4 nx[4];
#pragma unroll
  for (int i = 0; i < 4; ++i) {
    const int g  = t + i * NT;   // [b 16][j 16][p-f4 16]
    const int b  = g >> 8;
    const int jj = (g >> 4) & 15;
    const int c2 = g & 15;
    nx[i] = *reinterpret_cast<const float4*>(
        x + ((size_t)(bbase + b) * M + j0 + jj) * P + 4 * c2);
  }

  for (int c = 0; c < NCH; ++c) {
    if (c > 0) __syncthreads();  // obuf drain reads done -> xsh region free

    // ---- convert + write chunk c into swizzled xsh ----
#pragma unroll
    for (int i = 0; i < 4; ++i) {
      const int g  = t + i * NT;
      const int b  = g >> 8;
      const int jj = (g >> 4) & 15;
      const int c2 = g & 15;
      bf4 v;
      v[0] = (__bf16)nx[i].x; v[1] = (__bf16)nx[i].y;
      v[2] = (__bf16)nx[i].z; v[3] = (__bf16)nx[i].w;
      const int s = (c2 >> 1) ^ (b & 7);
      *reinterpret_cast<bf4*>(xsh + (((b << 4) + jj) << 6) + (s << 3) +
                              ((c2 & 1) << 2)) = v;
    }

    // ---- issue chunk c+1 global loads (land during compute/store) ----
    if (c < NCH - 1) {
      const int b0n = bbase + (c + 1) * BH;
#pragma unroll
      for (int i = 0; i < 4; ++i) {
        const int g  = t + i * NT;
        const int b  = g >> 8;
        const int jj = (g >> 4) & 15;
        const int c2 = g & 15;
        nx[i] = *reinterpret_cast<const float4*>(
            x + ((size_t)(b0n + b) * M + j0 + jj) * P + 4 * c2);
      }
    }

    __syncthreads();  // xsh visible

    // ---- compute: 2 A ds_read_b128 + 4 MFMA ----
    f32x4 acc[2];
#pragma unroll
    for (int nt = 0; nt < 2; ++nt)
      acc[nt] = f32x4{bv[nt], bv[nt], bv[nt], bv[nt]};

#pragma unroll
    for (int ks = 0; ks < 2; ++ks) {
      const int cc = ks * 4 + kg;
      const bf8 af = *reinterpret_cast<const bf8*>(
          xsh + (((col << 4) + wk) << 6) + ((cc ^ (col & 7)) << 3));
#pragma unroll
      for (int nt = 0; nt < 2; ++nt)
        acc[nt] = __builtin_amdgcn_mfma_f32_16x16x32_bf16(
            af, bfr[ks][nt], acc[nt], 0, 0, 0);
    }

    __syncthreads();  // xsh reads done before obuf overlay write

    // ---- obuf transpose write ----
#pragma unroll
    for (int nt = 0; nt < 2; ++nt) {
      const int w = nt * 16 + col;
      if (w < W) {
#pragma unroll
        for (int reg = 0; reg < 4; ++reg)
          obuf[(wk * 16 + kg * 4 + reg) * 25 + w] = acc[nt][reg];
      }
    }
    __syncthreads();  // obuf visible

    // ---- drain: 64B j-run float4 stores (1536 f4) ----
    const int b0c = bbase + c * BH;
#pragma unroll
    for (int it = 0; it < 2; ++it) {
      const int d = t + it * NT;
      if (d < 1536) {
        const int jq   = d & 3;
        const int rest = d >> 2;        // 0..383
        const int w    = rest % 24;
        const int br   = rest / 24;     // 0..15
        float4 o;
        o.x = obuf[((4 * jq + 0) * 16 + br) * 25 + w];
        o.y = obuf[((4 * jq + 1) * 16 + br) * 25 + w];
        o.z = obuf[((4 * jq + 2) * 16 + br) * 25 + w];
        o.w = obuf[((4 * jq + 3) * 16 + br) * 25 + w];
        *reinterpret_cast<float4*>(
            out + ((size_t)(b0c + br) * W + w) * M + j0 + 4 * jq) = o;
      }
    }
  }
}

extern "C" void kernel_launch(void* const* d_in, const int* in_sizes, int n_in,
                              void* d_out, int out_size, void* d_ws, size_t ws_size,
                              hipStream_t stream) {
  const float* x    = (const float*)d_in[0];
  const float* wgt  = (const float*)d_in[1];
  const float* bias = (const float*)d_in[2];
  float* out        = (float*)d_out;

  dim3 grid(NWG);  // 1250
  dim3 block(NT);  // 1024
  hipLaunchKernelGGL(pcl_kernel, grid, block, 0, stream, x, wgt, bias, out);
}